// Round 9
// baseline (1021.622 us; speedup 1.0000x reference)
//
#include <hip/hip_runtime.h>
#include <hip/hip_bf16.h>
#include <math.h>

#define HID   1024
#define IN_D  600
#define IN_DP 608      // 600 padded to multiple of 32
#define BATCH 2048
#define TSTEP 20
#define BT    (BATCH * TSTEP)   // 40960
#define G3    3072

typedef __attribute__((ext_vector_type(8))) short bf16x8;
typedef __attribute__((ext_vector_type(4))) float f32x4;

#define GLB(p) ((const __attribute__((address_space(1))) void*)(p))
#define LDS(p) ((__attribute__((address_space(3))) void*)(p))

__device__ __forceinline__ short f2bf(float f) {
    __hip_bfloat16 b = __float2bfloat16(f);
    return *(short*)&b;
}
__device__ __forceinline__ float bf2f(short s) {
    __hip_bfloat16 b = *(__hip_bfloat16*)&s;
    return __bfloat162float(b);
}

// ---------------------------------------------------------------------------
// Input projection: gx[m, n] = bf16( x_bf[m, :] . Wih[n, :] + b_ih[n] ),
// m = t*BATCH + b (x_bf pre-transposed), m97 structure. Epilogue stages C
// through LDS (aliasing sA/sB) -> coalesced bf16x8 global stores.
// ---------------------------------------------------------------------------
__global__ __launch_bounds__(256) void gemm_input(const short* __restrict__ X,
                                                  const short* __restrict__ W,
                                                  const float* __restrict__ b_ih,
                                                  short* __restrict__ gx) {
    __shared__ short smem[8192];
    short* sA = smem;          // 128 x 32
    short* sB = smem + 4096;   // 128 x 32

    const int id    = blockIdx.x;
    const int xcd   = id & 7;
    const int local = id >> 3;          // 0..959
    const int nsub  = local % 3;
    const int mblk  = local / 3;        // 0..319
    const int m0 = mblk * 128;
    const int n0 = (xcd * 3 + nsub) * 128;

    const int tid  = threadIdx.x;
    const int wave = tid >> 6;
    const int lane = tid & 63;
    const int wm = (wave >> 1) * 64;
    const int wn = (wave & 1) * 64;

    const int srow = tid >> 2;
    const int scol = (tid & 3) * 8;
    const int fm = lane & 15;
    const int fq = lane >> 4;

    f32x4 acc[4][4] = {};

    for (int k0 = 0; k0 < IN_DP; k0 += 32) {
#pragma unroll
        for (int j = 0; j < 2; ++j) {
            const short* ga = X + (size_t)(m0 + j * 64 + srow) * IN_DP + k0 + scol;
            __builtin_amdgcn_global_load_lds(GLB(ga), LDS(sA + j * 2048 + wave * 512), 16, 0, 0);
            const short* gb = W + (size_t)(n0 + j * 64 + srow) * IN_DP + k0 + scol;
            __builtin_amdgcn_global_load_lds(GLB(gb), LDS(sB + j * 2048 + wave * 512), 16, 0, 0);
        }
        __syncthreads();

        bf16x8 af[4], bf[4];
#pragma unroll
        for (int mi = 0; mi < 4; ++mi)
            af[mi] = *(const bf16x8*)(sA + (wm + mi * 16 + fm) * 32 + fq * 8);
#pragma unroll
        for (int ni = 0; ni < 4; ++ni)
            bf[ni] = *(const bf16x8*)(sB + (wn + ni * 16 + fm) * 32 + fq * 8);
#pragma unroll
        for (int mi = 0; mi < 4; ++mi)
#pragma unroll
            for (int ni = 0; ni < 4; ++ni)
                acc[mi][ni] = __builtin_amdgcn_mfma_f32_16x16x32_bf16(af[mi], bf[ni], acc[mi][ni], 0, 0, 0);
        __syncthreads();
    }

    // Epilogue: two passes over 64-col halves; C staged in LDS (smem reused),
    // then 128x64 bf16 tile stored with 16 B/lane fully-coalesced stores.
    short* sC = smem;                   // 128 x 64 shorts = 8192
    const int crow  = tid >> 1;         // 0..127
    const int chalf = tid & 1;
#pragma unroll
    for (int p = 0; p < 2; ++p) {
        __syncthreads();
        if ((wave & 1) == p) {          // waves whose wn == p*64
#pragma unroll
            for (int ni = 0; ni < 4; ++ni) {
                int coln = ni * 16 + fm;            // 0..63
                float bias = b_ih[n0 + p * 64 + coln];
#pragma unroll
                for (int mi = 0; mi < 4; ++mi)
#pragma unroll
                    for (int r = 0; r < 4; ++r)
                        sC[(wm + mi * 16 + fq * 4 + r) * 64 + coln] =
                            f2bf(acc[mi][ni][r] + bias);
            }
        }
        __syncthreads();
        const short* src = sC + crow * 64 + chalf * 32;
        short* dst = gx + (size_t)(m0 + crow) * G3 + n0 + p * 64 + chalf * 32;
#pragma unroll
        for (int v = 0; v < 4; ++v)
            *(bf16x8*)(dst + v * 8) = *(const bf16x8*)(src + v * 8);
    }
}

// ---------------------------------------------------------------------------
// Fused recurrent step v5: 128(batch) x 32(j) x 3 gates, BK=32, dbuf,
// LDS-only epilogue (gx tile prefetch + h snapshot from sA) — as v4, PLUS
// m-tile<->XCD affinity: xcd owns 2 m-tiles x all 32 j-blocks, so h[m-tile]
// is written (t-1) and read (t) within the SAME XCD's L2 — no h broadcast
// through L3. W_hh comes from L3 (static, resident).
// ---------------------------------------------------------------------------
__global__ __launch_bounds__(256) void gru_step(const short* __restrict__ hb_in,
                                                const short* __restrict__ Wr,
                                                const short* __restrict__ gx,
                                                const float* __restrict__ b_hh,
                                                short* __restrict__ hb_out,
                                                float* __restrict__ out,
                                                int t, int last) {
    __shared__ short sA[2][128 * 32];   // 2 x 8 KB   h k-chunks
    __shared__ short sB[2][96 * 32];    // 2 x 6 KB   W k-chunks (gate-interleaved)
    __shared__ short sGX[3 * 128 * 32]; // 24 KB      [gate][m][32 j]

    const int id    = blockIdx.x;
    const int xcd   = id & 7;
    const int local = id >> 3;          // 0..63
    const int j0 = (local & 31) * 32;              // all 32 j-blocks per XCD
    const int m0 = (xcd * 2 + (local >> 5)) * 128; // 2 m-tiles per XCD
    const int hchunk = j0 >> 5;         // k-chunk holding h[:, j0..j0+31]

    const int tid  = threadIdx.x;
    const int wave = tid >> 6;
    const int lane = tid & 63;
    const int wm = (wave >> 1) * 64;
    const int jg = wave & 1;
    const int fm = lane & 15;
    const int fq = lane >> 4;

    const int srow = lane >> 2;         // 0..15
    const int scol = (lane & 3) * 8;

    const short* Wblk = Wr + (size_t)(j0 * 3) * HID;   // 96 rows, K=1024
    const short* gxt  = gx + (size_t)t * BATCH * G3;

    // ---- prefetch gx tile into sGX (6 x 16B per thread, fire-and-forget) ----
#pragma unroll
    for (int it = 0; it < 6; ++it) {
        int q = it * 256 + tid;
        int g    = q >> 9;
        int rowq = (q & 511) >> 2;
        int cq   = (q & 3) * 8;
        const short* src = gxt + (size_t)(m0 + rowq) * G3 + g * HID + j0 + cq;
        __builtin_amdgcn_global_load_lds(GLB(src), LDS(sGX + it * 2048 + wave * 512), 16, 0, 0);
    }

    f32x4 acc[4][3] = {};    // [m-frag][gate]
    short hsnap[4][4];       // h[m-frag rows][this lane's j]

    auto stage = [&](int kc, int bsel) {
        int k0 = kc * 32;
#pragma unroll
        for (int jj = 0; jj < 2; ++jj) {
            int row = wave * 32 + jj * 16;
            const short* g = hb_in + (size_t)(m0 + row + srow) * HID + k0 + scol;
            __builtin_amdgcn_global_load_lds(GLB(g), LDS(&sA[bsel][row * 32]), 16, 0, 0);
        }
        if (wave < 3) {
#pragma unroll
            for (int jj = 0; jj < 2; ++jj) {
                int row = wave * 32 + jj * 16;
                const short* g = Wblk + (size_t)(row + srow) * HID + k0 + scol;
                __builtin_amdgcn_global_load_lds(GLB(g), LDS(&sB[bsel][row * 32]), 16, 0, 0);
            }
        }
    };

    const int jj = jg * 16 + fm;        // block-local j (0..31)

    stage(0, 0);
    for (int ic = 0; ic < 32; ++ic) {
        int cur = ic & 1;
        __syncthreads();                 // drains staging for buf cur (+ sGX on ic=0)
        if (ic + 1 < 32) stage(ic + 1, cur ^ 1);

        if (ic == hchunk) {              // snapshot h[:, j0..j0+31] from sA
#pragma unroll
            for (int mi = 0; mi < 4; ++mi)
#pragma unroll
                for (int r = 0; r < 4; ++r)
                    hsnap[mi][r] = sA[cur][(wm + mi * 16 + fq * 4 + r) * 32 + jj];
        }

        bf16x8 af[4], bg[3];
#pragma unroll
        for (int mi = 0; mi < 4; ++mi)
            af[mi] = *(const bf16x8*)(&sA[cur][(wm + mi * 16 + fm) * 32 + fq * 8]);
#pragma unroll
        for (int g = 0; g < 3; ++g)
            bg[g] = *(const bf16x8*)(&sB[cur][(jg * 48 + g * 16 + fm) * 32 + fq * 8]);
#pragma unroll
        for (int mi = 0; mi < 4; ++mi)
#pragma unroll
            for (int g = 0; g < 3; ++g)
                acc[mi][g] = __builtin_amdgcn_mfma_f32_16x16x32_bf16(af[mi], bg[g], acc[mi][g], 0, 0, 0);
    }

    // Epilogue: LDS/register-only inputs; global STORES only.
    const int jlane = j0 + jj;
    const float bh_r = b_hh[jlane];
    const float bh_i = b_hh[HID + jlane];
    const float bh_n = b_hh[2 * HID + jlane];

#pragma unroll
    for (int mi = 0; mi < 4; ++mi) {
#pragma unroll
        for (int r = 0; r < 4; ++r) {
            int mloc = wm + mi * 16 + fq * 4 + r;
            int gm = m0 + mloc;
            float xr = bf2f(sGX[mloc * 32 + jj]);
            float xi = bf2f(sGX[4096 + mloc * 32 + jj]);
            float xn = bf2f(sGX[8192 + mloc * 32 + jj]);

            float rg = 1.0f / (1.0f + __expf(-(xr + acc[mi][0][r] + bh_r)));
            float ig = 1.0f / (1.0f + __expf(-(xi + acc[mi][1][r] + bh_i)));
            float ng = tanhf(xn + rg * (acc[mi][2][r] + bh_n));

            float h  = bf2f(hsnap[mi][r]);
            float hy = ng + ig * (h - ng);
            size_t idx = (size_t)gm * HID + jlane;
            hb_out[idx] = f2bf(hy);
            if (last) out[idx] = hy;
        }
    }
}

// x [b][t][600] fp32 -> x_bf [t*B + b][608] bf16 zero-padded (transpose)
__global__ __launch_bounds__(256) void cvt_x(const float* __restrict__ X, short* __restrict__ Xb) {
    int rd = blockIdx.x;             // dst row = t*BATCH + b
    int tt = rd >> 11;               // /2048
    int b  = rd & (BATCH - 1);
    const float* s = X + ((size_t)b * TSTEP + tt) * IN_D;
    short* d = Xb + (size_t)rd * IN_DP;
    for (int c = threadIdx.x; c < IN_DP; c += 256)
        d[c] = (c < IN_D) ? f2bf(s[c]) : (short)0;
}

// Merged weight conversion:
//  bid < G3 : W_ih row -> [3072,608] bf16 zero-padded
//  bid >= G3: Wr gate-block-interleaved row: Wr[jb*48+g*16+ji] = Whh[g*1024+jb*16+ji]
__global__ __launch_bounds__(256) void cvt_weights(const float* __restrict__ Wih,
                                                   const float* __restrict__ Whh,
                                                   short* __restrict__ Wihb,
                                                   short* __restrict__ Wr) {
    int bid = blockIdx.x;
    if (bid < G3) {
        int r = bid;
        for (int c = threadIdx.x; c < IN_DP; c += 256) {
            float v = (c < IN_D) ? Wih[(size_t)r * IN_D + c] : 0.f;
            Wihb[(size_t)r * IN_DP + c] = f2bf(v);
        }
    } else {
        int n  = bid - G3;
        int jb = n / 48;
        int rem = n - jb * 48;
        int g  = rem >> 4;
        int ji = rem & 15;
        const float* s = Whh + (size_t)(g * HID + jb * 16 + ji) * HID;
        short* d = Wr + (size_t)n * HID;
        for (int c = threadIdx.x; c < HID; c += 256) d[c] = f2bf(s[c]);
    }
}

extern "C" void kernel_launch(void* const* d_in, const int* in_sizes, int n_in,
                              void* d_out, int out_size, void* d_ws, size_t ws_size,
                              hipStream_t stream) {
    const float* x    = (const float*)d_in[0];  // [B, T, IN_D]
    const float* W_ih = (const float*)d_in[1];  // [3H, IN_D]
    const float* b_ih = (const float*)d_in[2];
    const float* W_hh = (const float*)d_in[3];  // [3H, HID]
    const float* b_hh = (const float*)d_in[4];
    float* out = (float*)d_out;                 // [B, HID]

    char* p = (char*)d_ws;
    short* gx     = (short*)p;  p += (size_t)BT * G3 * 2;       // 251.7 MB, [t][b][3H]
    short* x_bf   = (short*)p;  p += (size_t)BT * IN_DP * 2;    //  49.8 MB, [t][b][608]
    short* hb0    = (short*)p;  p += (size_t)BATCH * HID * 2;   //   4.2 MB
    short* hb1    = (short*)p;  p += (size_t)BATCH * HID * 2;   //   4.2 MB
    short* Wih_bf = (short*)p;  p += (size_t)G3 * IN_DP * 2;    //   3.7 MB
    short* Whh_r  = (short*)p;  p += (size_t)G3 * HID * 2;      //   6.3 MB
    // total ~320 MB

    cvt_weights<<<2 * G3, 256, 0, stream>>>(W_ih, W_hh, Wih_bf, Whh_r);
    cvt_x<<<BT, 256, 0, stream>>>(x, x_bf);
    hipMemsetAsync(hb0, 0, (size_t)BATCH * HID * 2, stream);

    // One big input projection over all timesteps (M = 40960, 1D swizzled)
    gemm_input<<<7680, 256, 0, stream>>>(x_bf, Wih_bf, b_ih, gx);

    // 20 fused recurrent steps (512 blocks each, m-tile<->XCD affinity)
    for (int t = 0; t < TSTEP; ++t) {
        const short* hin = (t & 1) ? hb1 : hb0;
        short* hout      = (t & 1) ? hb0 : hb1;
        gru_step<<<512, 256, 0, stream>>>(hin, Whh_r, gx, b_hh,
                                          hout, out, t, t == TSTEP - 1 ? 1 : 0);
    }
}